// Round 2
// baseline (14241.891 us; speedup 1.0000x reference)
//
#include <hip/hip_runtime.h>
#include <math.h>

#define B   256
#define LT  128
#define LP  64
#define DM  512
#define D3  1536
#define DPH 80
#define SCALE_F 0.044194173824159216f   // 1/sqrt(512)

__device__ __forceinline__ float dot4(float4 a, float4 b) {
    return a.x*b.x + a.y*b.y + a.z*b.z + a.w*b.w;
}
__device__ __forceinline__ float sigmoidf_(float x) {
    return 1.0f / (1.0f + expf(-x));
}

// ---------------------------------------------------------------------------
// Precompute G[r][n] = bias[n] + sum_j Emb[r][j] * W[n*wstride + woff + j]
// (input-side GRU GEMM folded into an embedding-table-sized lookup table)
// grid: (1536/256, R/4), block 256
// ---------------------------------------------------------------------------
__global__ __launch_bounds__(256) void precompG_kernel(
    const float* __restrict__ Emb, const float* __restrict__ W,
    const float* __restrict__ bias, float* __restrict__ G,
    int wstride, int woff)
{
    const int n  = blockIdx.x * 256 + threadIdx.x;
    const int r0 = blockIdx.y * 4;
    __shared__ float es[4][DM];
    for (int i = threadIdx.x; i < 4 * DM; i += 256)
        es[i >> 9][i & 511] = Emb[(r0 + (i >> 9)) * DM + (i & 511)];
    __syncthreads();
    float acc[4] = {0.f, 0.f, 0.f, 0.f};
    const float* wr = &W[(size_t)n * wstride + woff];
    for (int j = 0; j < DM; j += 4) {
        float4 w4 = *(const float4*)&wr[j];
        #pragma unroll
        for (int rr = 0; rr < 4; ++rr) {
            float4 e4 = *(const float4*)&es[rr][j];
            acc[rr] += dot4(e4, w4);
        }
    }
    float bv = bias[n];
    #pragma unroll
    for (int rr = 0; rr < 4; ++rr)
        G[(r0 + rr) * D3 + n] = acc[rr] + bv;
}

// ---------------------------------------------------------------------------
// One encoder GRU step, both directions (blockIdx.z). Fused gh-GEMM + GRU.
// Output ys goes into interleaved E[row r=(b*LT+t)][1024]: fwd cols 0:512,
// bwd cols 512:1024.
// Tiling: M_t=32 (batch), J_t=32 (hidden cols, all 3 gates) -> grid (16,8,2)
// ---------------------------------------------------------------------------
__global__ __launch_bounds__(256) void enc_step_kernel(
    const float* __restrict__ Gf, const float* __restrict__ Gb,
    const float* __restrict__ Whh_f, const float* __restrict__ Whh_b,
    const float* __restrict__ bhh_f, const float* __restrict__ bhh_b,
    const int* __restrict__ text,
    const float* __restrict__ hF_in, float* __restrict__ hF_out,
    const float* __restrict__ hB_in, float* __restrict__ hB_out,
    float* __restrict__ E,
    int s)
{
    const int dir = blockIdx.z;
    const int t   = (dir == 0) ? s : (LT - 1 - s);
    const int yoff = (dir == 0) ? 0 : DM;
    const float* G   = (dir == 0) ? Gf    : Gb;
    const float* Whh = (dir == 0) ? Whh_f : Whh_b;
    const float* bhh = (dir == 0) ? bhh_f : bhh_b;
    const float* hin = (dir == 0) ? hF_in : hB_in;
    float* hout      = (dir == 0) ? hF_out : hB_out;

    __shared__ float As[32][36];   // pad 36: b128-aligned rows, 2-way max conflict
    __shared__ float Bs[96][36];

    const int tid = threadIdx.x;
    const int jj  = tid & 15;      // j lane (strided j = jj + 16*js)
    const int bb  = tid >> 4;      // b group (2 rows each)
    const int jtile = blockIdx.x * 32;
    const int btile = blockIdx.y * 32;

    float acc[2][2][3];
    #pragma unroll
    for (int m = 0; m < 2; ++m)
        #pragma unroll
        for (int js = 0; js < 2; ++js)
            #pragma unroll
            for (int g = 0; g < 3; ++g) acc[m][js][g] = 0.f;

    const int lrow = tid >> 3;
    const int lcol = (tid & 7) * 4;

    for (int k0 = 0; k0 < DM; k0 += 32) {
        __syncthreads();
        *(float4*)&As[lrow][lcol] =
            *(const float4*)&hin[(btile + lrow) * DM + k0 + lcol];
        #pragma unroll
        for (int rr = 0; rr < 3; ++rr) {
            int brow = lrow + rr * 32;            // 0..95
            int g = brow >> 5, j2 = brow & 31;
            *(float4*)&Bs[brow][lcol] =
                *(const float4*)&Whh[(g * DM + jtile + j2) * DM + k0 + lcol];
        }
        __syncthreads();
        #pragma unroll
        for (int c4 = 0; c4 < 8; ++c4) {
            float4 av[2], bv[2][3];
            #pragma unroll
            for (int m = 0; m < 2; ++m)
                av[m] = *(float4*)&As[bb * 2 + m][c4 * 4];
            #pragma unroll
            for (int js = 0; js < 2; ++js)
                #pragma unroll
                for (int g = 0; g < 3; ++g)
                    bv[js][g] = *(float4*)&Bs[g * 32 + jj + 16 * js][c4 * 4];
            #pragma unroll
            for (int m = 0; m < 2; ++m)
                #pragma unroll
                for (int js = 0; js < 2; ++js)
                    #pragma unroll
                    for (int g = 0; g < 3; ++g)
                        acc[m][js][g] += dot4(av[m], bv[js][g]);
        }
    }

    #pragma unroll
    for (int m = 0; m < 2; ++m) {
        const int b = btile + bb * 2 + m;
        const int c = text[b * LT + t];
        #pragma unroll
        for (int js = 0; js < 2; ++js) {
            const int j = jtile + jj + 16 * js;
            float hr = acc[m][js][0] + bhh[j];
            float hz = acc[m][js][1] + bhh[DM + j];
            float hn = acc[m][js][2] + bhh[2 * DM + j];
            float gr = G[c * D3 + j];
            float gz = G[c * D3 + DM + j];
            float gn = G[c * D3 + 2 * DM + j];
            float r = sigmoidf_(gr + hr);
            float z = sigmoidf_(gz + hz);
            float n = tanhf(gn + r * hn);
            float hp = hin[b * DM + j];
            float hv = (1.f - z) * n + z * hp;
            hout[b * DM + j] = hv;
            E[(size_t)(b * LT + t) * 1024 + yoff + j] = hv;
        }
    }
}

// ---------------------------------------------------------------------------
// Chunked k/v projection, written to temp T (then copied in-place over E).
// For chunk rows [r0, r0+2048): T[lm][0:512] = k, T[lm][512:1024] = v.
// k = E_row @ wk_W.T + wk_b ; v likewise. Tile 64x64(x2), kc=32. grid (8,32)
// ---------------------------------------------------------------------------
__global__ __launch_bounds__(256) void kv_chunk_kernel(
    const float* __restrict__ E,
    const float* __restrict__ wk, const float* __restrict__ wv,
    const float* __restrict__ kb, const float* __restrict__ vb,
    float* __restrict__ T, int r0)
{
    __shared__ float As[64][36];
    __shared__ float Bk[64][36];
    __shared__ float Bv[64][36];
    const int tid = threadIdx.x;
    const int nn = tid & 15, bb = tid >> 4;
    const int ntile = blockIdx.x * 64;
    const int mtile = blockIdx.y * 64;   // local row within chunk

    float ak[4][4], av_[4][4];
    #pragma unroll
    for (int m = 0; m < 4; ++m)
        #pragma unroll
        for (int i = 0; i < 4; ++i) { ak[m][i] = 0.f; av_[m][i] = 0.f; }

    const int lrow = tid >> 3;
    const int lcol = (tid & 7) * 4;

    for (int k0 = 0; k0 < 1024; k0 += 32) {
        __syncthreads();
        *(float4*)&As[lrow][lcol] =
            *(const float4*)&E[(size_t)(r0 + mtile + lrow) * 1024 + k0 + lcol];
        *(float4*)&As[lrow + 32][lcol] =
            *(const float4*)&E[(size_t)(r0 + mtile + lrow + 32) * 1024 + k0 + lcol];
        *(float4*)&Bk[lrow][lcol] =
            *(const float4*)&wk[(ntile + lrow) * 1024 + k0 + lcol];
        *(float4*)&Bk[lrow + 32][lcol] =
            *(const float4*)&wk[(ntile + lrow + 32) * 1024 + k0 + lcol];
        *(float4*)&Bv[lrow][lcol] =
            *(const float4*)&wv[(ntile + lrow) * 1024 + k0 + lcol];
        *(float4*)&Bv[lrow + 32][lcol] =
            *(const float4*)&wv[(ntile + lrow + 32) * 1024 + k0 + lcol];
        __syncthreads();
        #pragma unroll
        for (int c4 = 0; c4 < 8; ++c4) {
            float4 a4[4], k4[4], v4[4];
            #pragma unroll
            for (int m = 0; m < 4; ++m) a4[m] = *(float4*)&As[bb + 16 * m][c4 * 4];
            #pragma unroll
            for (int i = 0; i < 4; ++i) {
                k4[i] = *(float4*)&Bk[nn + 16 * i][c4 * 4];
                v4[i] = *(float4*)&Bv[nn + 16 * i][c4 * 4];
            }
            #pragma unroll
            for (int m = 0; m < 4; ++m)
                #pragma unroll
                for (int i = 0; i < 4; ++i) {
                    ak[m][i]  += dot4(a4[m], k4[i]);
                    av_[m][i] += dot4(a4[m], v4[i]);
                }
        }
    }
    #pragma unroll
    for (int m = 0; m < 4; ++m) {
        const int lm = mtile + bb + 16 * m;
        #pragma unroll
        for (int i = 0; i < 4; ++i) {
            const int gn = ntile + nn + 16 * i;
            T[(size_t)lm * 1024 + gn]       = ak[m][i]  + kb[gn];
            T[(size_t)lm * 1024 + DM + gn]  = av_[m][i] + vb[gn];
        }
    }
}

// ---------------------------------------------------------------------------
// h0 = tanh([hF|hB] @ hpost_W.T + hpost_b). One block per batch row.
// ---------------------------------------------------------------------------
__global__ __launch_bounds__(256) void hpost_kernel(
    const float* __restrict__ hF, const float* __restrict__ hB,
    const float* __restrict__ W, const float* __restrict__ bias,
    float* __restrict__ out)
{
    const int b = blockIdx.x;
    __shared__ float as_[1024];
    for (int i = threadIdx.x; i < DM; i += 256) {
        as_[i]      = hF[b * DM + i];
        as_[DM + i] = hB[b * DM + i];
    }
    __syncthreads();
    for (int n = threadIdx.x; n < DM; n += 256) {
        const float* wr = &W[n * 1024];
        float acc = 0.f;
        for (int j = 0; j < 1024; j += 4)
            acc += dot4(*(const float4*)&as_[j], *(const float4*)&wr[j]);
        out[b * DM + n] = tanhf(acc + bias[n]);
    }
}

// ---------------------------------------------------------------------------
// Decoder GRU step (x update). Two K-phases: A=a_o w/ dec_Wih[:,512:],
// A=h w/ dec_Whh. n-gate input/hidden parts kept separate (r multiplies hn).
// Tile M_t=32, J_t=32 -> grid (16, 8)
// ---------------------------------------------------------------------------
__global__ __launch_bounds__(256) void dec_step_kernel(
    const float* __restrict__ Gd,
    const float* __restrict__ dec_Wih, const float* __restrict__ dec_Whh,
    const float* __restrict__ bhh,
    const int* __restrict__ dec_i,
    const float* __restrict__ a_o,
    const float* __restrict__ h_in, float* __restrict__ h_out)
{
    __shared__ float As[32][36];
    __shared__ float Bs[96][36];
    const int tid = threadIdx.x;
    const int jj = tid & 15, bb = tid >> 4;
    const int jtile = blockIdx.x * 32;
    const int btile = blockIdx.y * 32;

    float acc[2][2][4];   // 0:r 1:z 2:inn(input) 3:hn(hidden)
    #pragma unroll
    for (int m = 0; m < 2; ++m)
        #pragma unroll
        for (int js = 0; js < 2; ++js)
            #pragma unroll
            for (int g = 0; g < 4; ++g) acc[m][js][g] = 0.f;

    const int lrow = tid >> 3;
    const int lcol = (tid & 7) * 4;

    for (int phase = 0; phase < 2; ++phase) {
        const float* Aptr = (phase == 0) ? a_o : h_in;
        for (int k0 = 0; k0 < DM; k0 += 32) {
            __syncthreads();
            *(float4*)&As[lrow][lcol] =
                *(const float4*)&Aptr[(btile + lrow) * DM + k0 + lcol];
            #pragma unroll
            for (int rr = 0; rr < 3; ++rr) {
                int brow = lrow + rr * 32;
                int g = brow >> 5, j2 = brow & 31;
                int wrow = g * DM + jtile + j2;
                float4 w4 = (phase == 0)
                    ? *(const float4*)&dec_Wih[wrow * 1024 + DM + k0 + lcol]
                    : *(const float4*)&dec_Whh[wrow * DM + k0 + lcol];
                *(float4*)&Bs[brow][lcol] = w4;
            }
            __syncthreads();
            #pragma unroll
            for (int c4 = 0; c4 < 8; ++c4) {
                float4 av[2], bv[2][3];
                #pragma unroll
                for (int m = 0; m < 2; ++m)
                    av[m] = *(float4*)&As[bb * 2 + m][c4 * 4];
                #pragma unroll
                for (int js = 0; js < 2; ++js)
                    #pragma unroll
                    for (int g = 0; g < 3; ++g)
                        bv[js][g] = *(float4*)&Bs[g * 32 + jj + 16 * js][c4 * 4];
                #pragma unroll
                for (int m = 0; m < 2; ++m)
                    #pragma unroll
                    for (int js = 0; js < 2; ++js) {
                        acc[m][js][0] += dot4(av[m], bv[js][0]);
                        acc[m][js][1] += dot4(av[m], bv[js][1]);
                        acc[m][js][2 + phase] += dot4(av[m], bv[js][2]);
                    }
            }
        }
    }

    #pragma unroll
    for (int m = 0; m < 2; ++m) {
        const int b = btile + bb * 2 + m;
        const int c = dec_i[b];
        #pragma unroll
        for (int js = 0; js < 2; ++js) {
            const int j = jtile + jj + 16 * js;
            float r = sigmoidf_(Gd[c * D3 + j] + bhh[j] + acc[m][js][0]);
            float z = sigmoidf_(Gd[c * D3 + DM + j] + bhh[DM + j] + acc[m][js][1]);
            float n = tanhf(Gd[c * D3 + 2 * DM + j] + acc[m][js][2]
                            + r * (acc[m][js][3] + bhh[2 * DM + j]));
            float hp = h_in[b * DM + j];
            h_out[b * DM + j] = (1.f - z) * n + z * hp;
        }
    }
}

// ---------------------------------------------------------------------------
// Decoder tail: logits+argmax (do_post) and attention (do_attn).
// K row r lives at EKV[r*1024], V row at EKV[r*1024+512].
// One block per batch row. attn row (a_sl) is the carry -> written at s+1.
// ---------------------------------------------------------------------------
__global__ __launch_bounds__(256) void dec_attend_post_kernel(
    const float* __restrict__ q,
    const float* __restrict__ EKV,
    const float* __restrict__ post_W, const float* __restrict__ post_b,
    float* __restrict__ attn, float* __restrict__ res,
    float* __restrict__ a_o, int* __restrict__ dec_i,
    int s, int attn_row, int do_post, int do_attn)
{
    const int b = blockIdx.x;
    const int tid = threadIdx.x;
    __shared__ float qs[DM];
    __shared__ float sarr[LT];
    __shared__ float red[2];

    for (int i = tid; i < DM; i += 256) qs[i] = q[b * DM + i];
    __syncthreads();

    if (do_post) {
        if (tid < DPH) {
            const float* wr = &post_W[tid * DM];
            float acc = 0.f;
            for (int d = 0; d < DM; d += 4)
                acc += dot4(*(const float4*)&qs[d], *(const float4*)&wr[d]);
            float lv = acc + post_b[tid];
            res[(b * LP + s) * DPH + tid] = lv;
            sarr[tid] = lv;
        }
        __syncthreads();
        if (tid == 0) {   // first-occurrence argmax, matching jnp.argmax
            float best = sarr[0]; int bi = 0;
            for (int p = 1; p < DPH; ++p) {
                float vv = sarr[p];
                if (vv > best) { best = vv; bi = p; }
            }
            dec_i[b] = bi;
        }
        __syncthreads();
    }

    if (do_attn) {
        float sc = 0.f, e = 0.f;
        if (tid < LT) {
            const float* kr = &EKV[(size_t)(b * LT + tid) * 1024];
            float acc = 0.f;
            for (int d = 0; d < DM; d += 4)
                acc += dot4(*(const float4*)&qs[d], *(const float4*)&kr[d]);
            sc = acc * SCALE_F;
            sarr[tid] = sc;
        }
        __syncthreads();
        if (tid < 64) {
            float m = fmaxf(sarr[tid], sarr[tid + 64]);
            #pragma unroll
            for (int off = 32; off > 0; off >>= 1)
                m = fmaxf(m, __shfl_xor(m, off));
            if (tid == 0) red[0] = m;
        }
        __syncthreads();
        const float smax = red[0];
        if (tid < LT) { e = expf(sc - smax); sarr[tid] = e; }
        __syncthreads();
        if (tid < 64) {
            float ssum = sarr[tid] + sarr[tid + 64];
            #pragma unroll
            for (int off = 32; off > 0; off >>= 1)
                ssum += __shfl_xor(ssum, off);
            if (tid == 0) red[1] = ssum;
        }
        __syncthreads();
        const float inv = 1.0f / red[1];
        if (tid < LT) {
            float a = e * inv;
            sarr[tid] = a;
            attn[(b * LP + attn_row) * LT + tid] = a;
        }
        __syncthreads();
        if (tid < 128) {   // o = a @ v, float4 per thread over d
            float4 acc = make_float4(0.f, 0.f, 0.f, 0.f);
            const float* vb0 = &EKV[(size_t)b * LT * 1024 + DM];
            for (int l = 0; l < LT; ++l) {
                float a = sarr[l];
                float4 v4 = *(const float4*)&vb0[(size_t)l * 1024 + tid * 4];
                acc.x += a * v4.x; acc.y += a * v4.y;
                acc.z += a * v4.z; acc.w += a * v4.w;
            }
            *(float4*)&a_o[b * DM + tid * 4] = acc;
        }
    }
}

// ---------------------------------------------------------------------------
extern "C" void kernel_launch(void* const* d_in, const int* in_sizes, int n_in,
                              void* d_out, int out_size, void* d_ws, size_t ws_size,
                              hipStream_t stream)
{
    const int*   text    = (const int*)d_in[0];
    // d_in[1] = tgt: only its shape (LP) is used by the reference
    const float* E_alpha = (const float*)d_in[2];
    const float* Wih_f   = (const float*)d_in[3];
    const float* Whh_f   = (const float*)d_in[4];
    const float* bih_f   = (const float*)d_in[5];
    const float* bhh_f   = (const float*)d_in[6];
    const float* Wih_b   = (const float*)d_in[7];
    const float* Whh_b   = (const float*)d_in[8];
    const float* bih_b   = (const float*)d_in[9];
    const float* bhh_b   = (const float*)d_in[10];
    const float* hpost_W = (const float*)d_in[11];
    const float* hpost_b = (const float*)d_in[12];
    const float* wk_W    = (const float*)d_in[13];
    const float* wk_b    = (const float*)d_in[14];
    const float* wv_W    = (const float*)d_in[15];
    const float* wv_b    = (const float*)d_in[16];
    const float* E_ph    = (const float*)d_in[17];
    const float* dec_Wih = (const float*)d_in[18];
    const float* dec_Whh = (const float*)d_in[19];
    const float* dec_bih = (const float*)d_in[20];
    const float* dec_bhh = (const float*)d_in[21];
    const float* post_W  = (const float*)d_in[22];
    const float* post_b  = (const float*)d_in[23];

    float* ws = (float*)d_ws;
    float* Gf  = ws;                 // 100*1536
    float* Gb  = Gf  + 153600;       // 100*1536
    float* Gd  = Gb  + 153600;       // 80*1536
    float* hF0 = Gd  + 122880;       // 256*512 x2 ping-pong
    float* hF1 = hF0 + 131072;
    float* hB0 = hF1 + 131072;
    float* hB1 = hB0 + 131072;
    float* hd0 = hB1 + 131072;       // decoder hidden ping-pong
    float* hd1 = hd0 + 131072;
    float* a_o = hd1 + 131072;       // 256*512
    int*   dec_i = (int*)(a_o + 131072);
    float* E   = a_o + 131072 + 512; // 32768*1024: ys, then in-place K|V
    float* T   = E + 33554432;       // 2048*1024 chunk temp
    // total ~148 MB of workspace

    hipMemsetAsync(hF0, 0, 131072 * sizeof(float), stream);
    hipMemsetAsync(hB0, 0, 131072 * sizeof(float), stream);
    hipMemsetAsync(dec_i, 0, B * sizeof(int), stream);

    // Fold input-side GRU GEMMs into per-token lookup tables
    precompG_kernel<<<dim3(6, 25), 256, 0, stream>>>(E_alpha, Wih_f, bih_f, Gf, DM, 0);
    precompG_kernel<<<dim3(6, 25), 256, 0, stream>>>(E_alpha, Wih_b, bih_b, Gb, DM, 0);
    precompG_kernel<<<dim3(6, 20), 256, 0, stream>>>(E_ph, dec_Wih, dec_bih, Gd, 1024, 0);

    // Bidirectional encoder: 128 steps, both directions per launch
    for (int s = 0; s < LT; ++s) {
        const float* fin = (s & 1) ? hF1 : hF0;
        float*       fou = (s & 1) ? hF0 : hF1;
        const float* bin = (s & 1) ? hB1 : hB0;
        float*       bou = (s & 1) ? hB0 : hB1;
        enc_step_kernel<<<dim3(16, 8, 2), 256, 0, stream>>>(
            Gf, Gb, Whh_f, Whh_b, bhh_f, bhh_b, text,
            fin, fou, bin, bou, E, s);
    }
    // s=127 wrote into hF0/hB0 -> finals live there

    // In-place ys -> [K|V]: chunked GEMM into T, then copy back over E rows.
    for (int c = 0; c < 16; ++c) {
        const int r0 = c * 2048;
        kv_chunk_kernel<<<dim3(8, 32), 256, 0, stream>>>(
            E, wk_W, wv_W, wk_b, wv_b, T, r0);
        hipMemcpyAsync(E + (size_t)r0 * 1024, T,
                       (size_t)2048 * 1024 * sizeof(float),
                       hipMemcpyDeviceToDevice, stream);
    }

    hpost_kernel<<<dim3(B), 256, 0, stream>>>(hF0, hB0, hpost_W, hpost_b, hd0);

    float* attn = (float*)d_out;                  // (256,64,128)
    float* res  = attn + (size_t)B * LP * LT;     // (256,64,80)

    // a_sl0 = attend(h0): writes attn row 0 and a_o
    dec_attend_post_kernel<<<dim3(B), 256, 0, stream>>>(
        hd0, E, post_W, post_b, attn, res, a_o, dec_i,
        /*s=*/0, /*attn_row=*/0, /*do_post=*/0, /*do_attn=*/1);

    for (int s = 0; s < LP; ++s) {
        const float* hin = (s & 1) ? hd1 : hd0;
        float*       hou = (s & 1) ? hd0 : hd1;
        dec_step_kernel<<<dim3(16, 8), 256, 0, stream>>>(
            Gd, dec_Wih, dec_Whh, dec_bhh, dec_i, a_o, hin, hou);
        // logits for res[:,s,:], argmax feedback; attention of x_s -> attn[:,s+1,:]
        dec_attend_post_kernel<<<dim3(B), 256, 0, stream>>>(
            hou, E, post_W, post_b, attn, res, a_o, dec_i,
            s, s + 1, 1, (s < LP - 1) ? 1 : 0);
    }
}

// Round 3
// 11215.452 us; speedup vs baseline: 1.2698x; 1.2698x over previous
//
#include <hip/hip_runtime.h>
#include <math.h>

#define B   256
#define LT  128
#define LP  64
#define DM  512
#define D3  1536
#define DPH 80
#define SCALE_F 0.044194173824159216f   // 1/sqrt(512)

__device__ __forceinline__ float dot4(float4 a, float4 b) {
    return a.x*b.x + a.y*b.y + a.z*b.z + a.w*b.w;
}
__device__ __forceinline__ float sigmoidf_(float x) {
    return 1.0f / (1.0f + expf(-x));
}

// ---------------------------------------------------------------------------
// Precompute G[r][n] = bias[n] + sum_j Emb[r][j] * W[n*wstride + woff + j]
// grid: (1536/256, R/4), block 256
// ---------------------------------------------------------------------------
__global__ __launch_bounds__(256) void precompG_kernel(
    const float* __restrict__ Emb, const float* __restrict__ W,
    const float* __restrict__ bias, float* __restrict__ G,
    int wstride, int woff)
{
    const int n  = blockIdx.x * 256 + threadIdx.x;
    const int r0 = blockIdx.y * 4;
    __shared__ float es[4][DM];
    for (int i = threadIdx.x; i < 4 * DM; i += 256)
        es[i >> 9][i & 511] = Emb[(r0 + (i >> 9)) * DM + (i & 511)];
    __syncthreads();
    float acc[4] = {0.f, 0.f, 0.f, 0.f};
    const float* wr = &W[(size_t)n * wstride + woff];
    for (int j = 0; j < DM; j += 4) {
        float4 w4 = *(const float4*)&wr[j];
        #pragma unroll
        for (int rr = 0; rr < 4; ++rr) {
            float4 e4 = *(const float4*)&es[rr][j];
            acc[rr] += dot4(e4, w4);
        }
    }
    float bv = bias[n];
    #pragma unroll
    for (int rr = 0; rr < 4; ++rr)
        G[(r0 + rr) * D3 + n] = acc[rr] + bv;
}

// ---------------------------------------------------------------------------
// Encoder GRU step, both directions (blockIdx.z), double-buffered LDS.
// Tiling: M_t=32 (batch), J_t=32 -> grid (16,8,2). 1 barrier per k-iter;
// tile k+1 global loads overlap compute of tile k.
// ---------------------------------------------------------------------------
__global__ __launch_bounds__(256) void enc_step_kernel(
    const float* __restrict__ Gf, const float* __restrict__ Gb,
    const float* __restrict__ Whh_f, const float* __restrict__ Whh_b,
    const float* __restrict__ bhh_f, const float* __restrict__ bhh_b,
    const int* __restrict__ text,
    const float* __restrict__ hF_in, float* __restrict__ hF_out,
    const float* __restrict__ hB_in, float* __restrict__ hB_out,
    float* __restrict__ E,
    int s)
{
    const int dir = blockIdx.z;
    const int t   = (dir == 0) ? s : (LT - 1 - s);
    const int yoff = (dir == 0) ? 0 : DM;
    const float* G   = (dir == 0) ? Gf    : Gb;
    const float* Whh = (dir == 0) ? Whh_f : Whh_b;
    const float* bhh = (dir == 0) ? bhh_f : bhh_b;
    const float* hin = (dir == 0) ? hF_in : hB_in;
    float* hout      = (dir == 0) ? hF_out : hB_out;

    __shared__ float As[2][32][36];
    __shared__ float Bs[2][96][36];

    const int tid = threadIdx.x;
    const int jj  = tid & 15;
    const int bb  = tid >> 4;
    const int jtile = blockIdx.x * 32;
    const int btile = blockIdx.y * 32;

    float acc[2][2][3];
    #pragma unroll
    for (int m = 0; m < 2; ++m)
        #pragma unroll
        for (int js = 0; js < 2; ++js)
            #pragma unroll
            for (int g = 0; g < 3; ++g) acc[m][js][g] = 0.f;

    const int lrow = tid >> 3;
    const int lcol = (tid & 7) * 4;
    const int g_  = lrow >> 5;           // unused for As, reused per rr below

    // B-row mapping for the three Bs loads
    int wrow[3];
    #pragma unroll
    for (int rr = 0; rr < 3; ++rr) {
        int brow = lrow + rr * 32;
        wrow[rr] = (brow >> 5) * DM + jtile + (brow & 31);
    }
    (void)g_;

    // prefetch tile 0
    float4 rA = *(const float4*)&hin[(btile + lrow) * DM + lcol];
    float4 rB0 = *(const float4*)&Whh[(size_t)wrow[0] * DM + lcol];
    float4 rB1 = *(const float4*)&Whh[(size_t)wrow[1] * DM + lcol];
    float4 rB2 = *(const float4*)&Whh[(size_t)wrow[2] * DM + lcol];

    int buf = 0;
    for (int k = 0; k < 16; ++k) {
        *(float4*)&As[buf][lrow][lcol]      = rA;
        *(float4*)&Bs[buf][lrow][lcol]      = rB0;
        *(float4*)&Bs[buf][lrow + 32][lcol] = rB1;
        *(float4*)&Bs[buf][lrow + 64][lcol] = rB2;
        __syncthreads();
        if (k < 15) {
            const int k0 = (k + 1) * 32;
            rA  = *(const float4*)&hin[(btile + lrow) * DM + k0 + lcol];
            rB0 = *(const float4*)&Whh[(size_t)wrow[0] * DM + k0 + lcol];
            rB1 = *(const float4*)&Whh[(size_t)wrow[1] * DM + k0 + lcol];
            rB2 = *(const float4*)&Whh[(size_t)wrow[2] * DM + k0 + lcol];
        }
        #pragma unroll
        for (int c4 = 0; c4 < 8; ++c4) {
            float4 av[2], bv[2][3];
            #pragma unroll
            for (int m = 0; m < 2; ++m)
                av[m] = *(float4*)&As[buf][bb * 2 + m][c4 * 4];
            #pragma unroll
            for (int js = 0; js < 2; ++js)
                #pragma unroll
                for (int g = 0; g < 3; ++g)
                    bv[js][g] = *(float4*)&Bs[buf][g * 32 + jj + 16 * js][c4 * 4];
            #pragma unroll
            for (int m = 0; m < 2; ++m)
                #pragma unroll
                for (int js = 0; js < 2; ++js)
                    #pragma unroll
                    for (int g = 0; g < 3; ++g)
                        acc[m][js][g] += dot4(av[m], bv[js][g]);
        }
        buf ^= 1;
    }

    #pragma unroll
    for (int m = 0; m < 2; ++m) {
        const int b = btile + bb * 2 + m;
        const int c = text[b * LT + t];
        #pragma unroll
        for (int js = 0; js < 2; ++js) {
            const int j = jtile + jj + 16 * js;
            float hr = acc[m][js][0] + bhh[j];
            float hz = acc[m][js][1] + bhh[DM + j];
            float hn = acc[m][js][2] + bhh[2 * DM + j];
            float r = sigmoidf_(G[c * D3 + j] + hr);
            float z = sigmoidf_(G[c * D3 + DM + j] + hz);
            float n = tanhf(G[c * D3 + 2 * DM + j] + r * hn);
            float hp = hin[b * DM + j];
            float hv = (1.f - z) * n + z * hp;
            hout[b * DM + j] = hv;
            E[(size_t)(b * LT + t) * 1024 + yoff + j] = hv;
        }
    }
}

// ---------------------------------------------------------------------------
// Chunked k/v projection (rows [r0, r0+8192)), written to temp T then copied
// in-place over E. Tile 64x64(x2), kc=32. grid (8, 128)
// ---------------------------------------------------------------------------
__global__ __launch_bounds__(256) void kv_chunk_kernel(
    const float* __restrict__ E,
    const float* __restrict__ wk, const float* __restrict__ wv,
    const float* __restrict__ kb, const float* __restrict__ vb,
    float* __restrict__ T, int r0)
{
    __shared__ float As[64][36];
    __shared__ float Bk[64][36];
    __shared__ float Bv[64][36];
    const int tid = threadIdx.x;
    const int nn = tid & 15, bb = tid >> 4;
    const int ntile = blockIdx.x * 64;
    const int mtile = blockIdx.y * 64;

    float ak[4][4], av_[4][4];
    #pragma unroll
    for (int m = 0; m < 4; ++m)
        #pragma unroll
        for (int i = 0; i < 4; ++i) { ak[m][i] = 0.f; av_[m][i] = 0.f; }

    const int lrow = tid >> 3;
    const int lcol = (tid & 7) * 4;

    for (int k0 = 0; k0 < 1024; k0 += 32) {
        __syncthreads();
        *(float4*)&As[lrow][lcol] =
            *(const float4*)&E[(size_t)(r0 + mtile + lrow) * 1024 + k0 + lcol];
        *(float4*)&As[lrow + 32][lcol] =
            *(const float4*)&E[(size_t)(r0 + mtile + lrow + 32) * 1024 + k0 + lcol];
        *(float4*)&Bk[lrow][lcol] =
            *(const float4*)&wk[(ntile + lrow) * 1024 + k0 + lcol];
        *(float4*)&Bk[lrow + 32][lcol] =
            *(const float4*)&wk[(ntile + lrow + 32) * 1024 + k0 + lcol];
        *(float4*)&Bv[lrow][lcol] =
            *(const float4*)&wv[(ntile + lrow) * 1024 + k0 + lcol];
        *(float4*)&Bv[lrow + 32][lcol] =
            *(const float4*)&wv[(ntile + lrow + 32) * 1024 + k0 + lcol];
        __syncthreads();
        #pragma unroll
        for (int c4 = 0; c4 < 8; ++c4) {
            float4 a4[4], k4[4], v4[4];
            #pragma unroll
            for (int m = 0; m < 4; ++m) a4[m] = *(float4*)&As[bb + 16 * m][c4 * 4];
            #pragma unroll
            for (int i = 0; i < 4; ++i) {
                k4[i] = *(float4*)&Bk[nn + 16 * i][c4 * 4];
                v4[i] = *(float4*)&Bv[nn + 16 * i][c4 * 4];
            }
            #pragma unroll
            for (int m = 0; m < 4; ++m)
                #pragma unroll
                for (int i = 0; i < 4; ++i) {
                    ak[m][i]  += dot4(a4[m], k4[i]);
                    av_[m][i] += dot4(a4[m], v4[i]);
                }
        }
    }
    #pragma unroll
    for (int m = 0; m < 4; ++m) {
        const int lm = mtile + bb + 16 * m;
        #pragma unroll
        for (int i = 0; i < 4; ++i) {
            const int gn = ntile + nn + 16 * i;
            T[(size_t)lm * 1024 + gn]       = ak[m][i]  + kb[gn];
            T[(size_t)lm * 1024 + DM + gn]  = av_[m][i] + vb[gn];
        }
    }
}

// ---------------------------------------------------------------------------
// h0 = tanh([hF|hB] @ hpost_W.T + hpost_b). One block per batch row.
// ---------------------------------------------------------------------------
__global__ __launch_bounds__(256) void hpost_kernel(
    const float* __restrict__ hF, const float* __restrict__ hB,
    const float* __restrict__ W, const float* __restrict__ bias,
    float* __restrict__ out)
{
    const int b = blockIdx.x;
    __shared__ float as_[1024];
    for (int i = threadIdx.x; i < DM; i += 256) {
        as_[i]      = hF[b * DM + i];
        as_[DM + i] = hB[b * DM + i];
    }
    __syncthreads();
    for (int n = threadIdx.x; n < DM; n += 256) {
        const float* wr = &W[n * 1024];
        float acc = 0.f;
        for (int j = 0; j < 1024; j += 4)
            acc += dot4(*(const float4*)&as_[j], *(const float4*)&wr[j]);
        out[b * DM + n] = tanhf(acc + bias[n]);
    }
}

// ---------------------------------------------------------------------------
// Decoder GRU step: btile=16, jtile=32 -> grid (16,16) = 256 blocks (full
// chip), double-buffered LDS, linearized 32-iter loop over (phase, k0).
// phase 0: A=a_o vs dec_Wih[:,512:]; phase 1: A=h vs dec_Whh.
// ---------------------------------------------------------------------------
__global__ __launch_bounds__(256) void dec_step_kernel(
    const float* __restrict__ Gd,
    const float* __restrict__ dec_Wih, const float* __restrict__ dec_Whh,
    const float* __restrict__ bhh,
    const int* __restrict__ dec_i,
    const float* __restrict__ a_o,
    const float* __restrict__ h_in, float* __restrict__ h_out)
{
    __shared__ float As[2][16][36];
    __shared__ float Bs[2][96][36];
    const int tid = threadIdx.x;
    const int jj = tid & 15, bb = tid >> 4;
    const int jtile = blockIdx.x * 32;
    const int btile = blockIdx.y * 16;

    float acc[2][4];   // [js][0:r 1:z 2:inn 3:hn]
    #pragma unroll
    for (int js = 0; js < 2; ++js)
        #pragma unroll
        for (int g = 0; g < 4; ++g) acc[js][g] = 0.f;

    const int lrow  = tid >> 3;          // 0..31 (Bs), As uses tid<128
    const int lcol  = (tid & 7) * 4;
    const int lrowA = lrow;              // 0..15 for tid<128

    int wrow[3];
    #pragma unroll
    for (int rr = 0; rr < 3; ++rr) {
        int brow = lrow + rr * 32;
        wrow[rr] = (brow >> 5) * DM + jtile + (brow & 31);
    }

    // tile loader: kk in [0,32), phase = kk>>4, k0 = (kk&15)*32
    float4 rA = make_float4(0.f,0.f,0.f,0.f), rB0, rB1, rB2;
    {
        // kk = 0: phase 0
        if (tid < 128)
            rA = *(const float4*)&a_o[(btile + lrowA) * DM + lcol];
        rB0 = *(const float4*)&dec_Wih[(size_t)wrow[0] * 1024 + DM + lcol];
        rB1 = *(const float4*)&dec_Wih[(size_t)wrow[1] * 1024 + DM + lcol];
        rB2 = *(const float4*)&dec_Wih[(size_t)wrow[2] * 1024 + DM + lcol];
    }

    int buf = 0;
    for (int kk = 0; kk < 32; ++kk) {
        const int phase = kk >> 4;
        if (tid < 128)
            *(float4*)&As[buf][lrowA][lcol] = rA;
        *(float4*)&Bs[buf][lrow][lcol]      = rB0;
        *(float4*)&Bs[buf][lrow + 32][lcol] = rB1;
        *(float4*)&Bs[buf][lrow + 64][lcol] = rB2;
        __syncthreads();
        if (kk < 31) {
            const int nk = kk + 1;
            const int np = nk >> 4;
            const int k0 = (nk & 15) * 32;
            if (tid < 128) {
                const float* Aptr = (np == 0) ? a_o : h_in;
                rA = *(const float4*)&Aptr[(btile + lrowA) * DM + k0 + lcol];
            }
            if (np == 0) {
                rB0 = *(const float4*)&dec_Wih[(size_t)wrow[0] * 1024 + DM + k0 + lcol];
                rB1 = *(const float4*)&dec_Wih[(size_t)wrow[1] * 1024 + DM + k0 + lcol];
                rB2 = *(const float4*)&dec_Wih[(size_t)wrow[2] * 1024 + DM + k0 + lcol];
            } else {
                rB0 = *(const float4*)&dec_Whh[(size_t)wrow[0] * DM + k0 + lcol];
                rB1 = *(const float4*)&dec_Whh[(size_t)wrow[1] * DM + k0 + lcol];
                rB2 = *(const float4*)&dec_Whh[(size_t)wrow[2] * DM + k0 + lcol];
            }
        }
        #pragma unroll
        for (int c4 = 0; c4 < 8; ++c4) {
            float4 av = *(float4*)&As[buf][bb][c4 * 4];
            float4 bv[2][3];
            #pragma unroll
            for (int js = 0; js < 2; ++js)
                #pragma unroll
                for (int g = 0; g < 3; ++g)
                    bv[js][g] = *(float4*)&Bs[buf][g * 32 + jj + 16 * js][c4 * 4];
            #pragma unroll
            for (int js = 0; js < 2; ++js) {
                acc[js][0]         += dot4(av, bv[js][0]);
                acc[js][1]         += dot4(av, bv[js][1]);
                acc[js][2 + phase] += dot4(av, bv[js][2]);
            }
        }
        buf ^= 1;
    }

    const int b = btile + bb;
    const int c = dec_i[b];
    #pragma unroll
    for (int js = 0; js < 2; ++js) {
        const int j = jtile + jj + 16 * js;
        float r = sigmoidf_(Gd[c * D3 + j] + bhh[j] + acc[js][0]);
        float z = sigmoidf_(Gd[c * D3 + DM + j] + bhh[DM + j] + acc[js][1]);
        float n = tanhf(Gd[c * D3 + 2 * DM + j] + acc[js][2]
                        + r * (acc[js][3] + bhh[2 * DM + j]));
        float hp = h_in[b * DM + j];
        h_out[b * DM + j] = (1.f - z) * n + z * hp;
    }
}

// ---------------------------------------------------------------------------
// Decoder tail: logits+argmax (do_post) and attention (do_attn).
// K row r at EKV[r*1024], V row at EKV[r*1024+512]. One block per batch row.
// QK: d-split across thread pairs; PV: l-split halves with LDS combine.
// ---------------------------------------------------------------------------
__global__ __launch_bounds__(256) void dec_attend_post_kernel(
    const float* __restrict__ q,
    const float* __restrict__ EKV,
    const float* __restrict__ post_W, const float* __restrict__ post_b,
    float* __restrict__ attn, float* __restrict__ res,
    float* __restrict__ a_o, int* __restrict__ dec_i,
    int s, int attn_row, int do_post, int do_attn)
{
    const int b = blockIdx.x;
    const int tid = threadIdx.x;
    __shared__ float qs[DM];
    __shared__ float part[256];
    __shared__ float sarr[LT];
    __shared__ float red[2];
    __shared__ float4 pvp[2][128];

    if (tid < 128)
        *(float4*)&qs[tid * 4] = *(const float4*)&q[b * DM + tid * 4];
    __syncthreads();

    if (do_post) {
        if (tid < DPH) {
            const float* wr = &post_W[tid * DM];
            float acc = 0.f;
            for (int d = 0; d < DM; d += 4)
                acc += dot4(*(const float4*)&qs[d], *(const float4*)&wr[d]);
            float lv = acc + post_b[tid];
            res[(b * LP + s) * DPH + tid] = lv;
            part[tid] = lv;
        }
        __syncthreads();
        if (tid == 0) {   // first-occurrence argmax, matching jnp.argmax
            float best = part[0]; int bi = 0;
            for (int p = 1; p < DPH; ++p) {
                float vv = part[p];
                if (vv > best) { best = vv; bi = p; }
            }
            dec_i[b] = bi;
        }
        __syncthreads();
    }

    if (do_attn) {
        // --- scores: 2 threads per K-row (d-halves) ---
        {
            const int r = tid & 127, half = tid >> 7;
            const float* kr = &EKV[(size_t)(b * LT + r) * 1024 + half * 256];
            const float* qh = &qs[half * 256];
            float p = 0.f;
            #pragma unroll
            for (int d = 0; d < 256; d += 4)
                p += dot4(*(const float4*)&qh[d], *(const float4*)&kr[d]);
            part[tid] = p;
        }
        __syncthreads();
        if (tid < LT) sarr[tid] = (part[tid] + part[tid + 128]) * SCALE_F;
        __syncthreads();
        if (tid < 64) {
            float m = fmaxf(sarr[tid], sarr[tid + 64]);
            #pragma unroll
            for (int off = 32; off > 0; off >>= 1)
                m = fmaxf(m, __shfl_xor(m, off));
            if (tid == 0) red[0] = m;
        }
        __syncthreads();
        const float smax = red[0];
        if (tid < LT) sarr[tid] = expf(sarr[tid] - smax);
        __syncthreads();
        if (tid < 64) {
            float ssum = sarr[tid] + sarr[tid + 64];
            #pragma unroll
            for (int off = 32; off > 0; off >>= 1)
                ssum += __shfl_xor(ssum, off);
            if (tid == 0) red[1] = ssum;
        }
        __syncthreads();
        const float inv = 1.0f / red[1];
        if (tid < LT) {
            float a = sarr[tid] * inv;
            sarr[tid] = a;
            attn[(size_t)(b * LP + attn_row) * LT + tid] = a;
        }
        __syncthreads();
        // --- o = a @ V: 2 threads per d-float4 (l-halves) ---
        {
            const int d4 = tid & 127, half = tid >> 7;
            const float* vb0 = &EKV[(size_t)b * LT * 1024 + DM];
            float4 acc = make_float4(0.f, 0.f, 0.f, 0.f);
            const int l0 = half * 64;
            #pragma unroll 8
            for (int l = l0; l < l0 + 64; ++l) {
                float a = sarr[l];
                float4 v4 = *(const float4*)&vb0[(size_t)l * 1024 + d4 * 4];
                acc.x += a * v4.x; acc.y += a * v4.y;
                acc.z += a * v4.z; acc.w += a * v4.w;
            }
            pvp[half][d4] = acc;
        }
        __syncthreads();
        if (tid < 128) {
            float4 p0 = pvp[0][tid], p1 = pvp[1][tid];
            float4 o = make_float4(p0.x + p1.x, p0.y + p1.y,
                                   p0.z + p1.z, p0.w + p1.w);
            *(float4*)&a_o[b * DM + tid * 4] = o;
        }
    }
}

// ---------------------------------------------------------------------------
extern "C" void kernel_launch(void* const* d_in, const int* in_sizes, int n_in,
                              void* d_out, int out_size, void* d_ws, size_t ws_size,
                              hipStream_t stream)
{
    const int*   text    = (const int*)d_in[0];
    const float* E_alpha = (const float*)d_in[2];
    const float* Wih_f   = (const float*)d_in[3];
    const float* Whh_f   = (const float*)d_in[4];
    const float* bih_f   = (const float*)d_in[5];
    const float* bhh_f   = (const float*)d_in[6];
    const float* Wih_b   = (const float*)d_in[7];
    const float* Whh_b   = (const float*)d_in[8];
    const float* bih_b   = (const float*)d_in[9];
    const float* bhh_b   = (const float*)d_in[10];
    const float* hpost_W = (const float*)d_in[11];
    const float* hpost_b = (const float*)d_in[12];
    const float* wk_W    = (const float*)d_in[13];
    const float* wk_b    = (const float*)d_in[14];
    const float* wv_W    = (const float*)d_in[15];
    const float* wv_b    = (const float*)d_in[16];
    const float* E_ph    = (const float*)d_in[17];
    const float* dec_Wih = (const float*)d_in[18];
    const float* dec_Whh = (const float*)d_in[19];
    const float* dec_bih = (const float*)d_in[20];
    const float* dec_bhh = (const float*)d_in[21];
    const float* post_W  = (const float*)d_in[22];
    const float* post_b  = (const float*)d_in[23];

    float* ws = (float*)d_ws;
    float* Gf  = ws;                 // 100*1536
    float* Gb  = Gf  + 153600;       // 100*1536
    float* Gd  = Gb  + 153600;       // 80*1536
    float* hF0 = Gd  + 122880;       // 256*512 x2 ping-pong
    float* hF1 = hF0 + 131072;
    float* hB0 = hF1 + 131072;
    float* hB1 = hB0 + 131072;
    float* hd0 = hB1 + 131072;       // decoder hidden ping-pong
    float* hd1 = hd0 + 131072;
    float* a_o = hd1 + 131072;       // 256*512
    int*   dec_i = (int*)(a_o + 131072);
    float* E   = a_o + 131072 + 512; // 32768*1024: ys, then in-place K|V
    float* T   = E + 33554432;       // 8192*1024 chunk temp (32 MB)
    // total ~173 MB of workspace

    hipMemsetAsync(hF0, 0, 131072 * sizeof(float), stream);
    hipMemsetAsync(hB0, 0, 131072 * sizeof(float), stream);
    hipMemsetAsync(dec_i, 0, B * sizeof(int), stream);

    // Fold input-side GRU GEMMs into per-token lookup tables
    precompG_kernel<<<dim3(6, 25), 256, 0, stream>>>(E_alpha, Wih_f, bih_f, Gf, DM, 0);
    precompG_kernel<<<dim3(6, 25), 256, 0, stream>>>(E_alpha, Wih_b, bih_b, Gb, DM, 0);
    precompG_kernel<<<dim3(6, 20), 256, 0, stream>>>(E_ph, dec_Wih, dec_bih, Gd, 1024, 0);

    // Bidirectional encoder: 128 steps, both directions per launch
    for (int s = 0; s < LT; ++s) {
        const float* fin = (s & 1) ? hF1 : hF0;
        float*       fou = (s & 1) ? hF0 : hF1;
        const float* bin = (s & 1) ? hB1 : hB0;
        float*       bou = (s & 1) ? hB0 : hB1;
        enc_step_kernel<<<dim3(16, 8, 2), 256, 0, stream>>>(
            Gf, Gb, Whh_f, Whh_b, bhh_f, bhh_b, text,
            fin, fou, bin, bou, E, s);
    }
    // s=127 wrote into hF0/hB0 -> finals live there

    // In-place ys -> [K|V]: 4 chunks of 8192 rows
    for (int c = 0; c < 4; ++c) {
        const int r0 = c * 8192;
        kv_chunk_kernel<<<dim3(8, 128), 256, 0, stream>>>(
            E, wk_W, wv_W, wk_b, wv_b, T, r0);
        hipMemcpyAsync(E + (size_t)r0 * 1024, T,
                       (size_t)8192 * 1024 * sizeof(float),
                       hipMemcpyDeviceToDevice, stream);
    }

    hpost_kernel<<<dim3(B), 256, 0, stream>>>(hF0, hB0, hpost_W, hpost_b, hd0);

    float* attn = (float*)d_out;                  // (256,64,128)
    float* res  = attn + (size_t)B * LP * LT;     // (256,64,80)

    // a_sl0 = attend(h0): writes attn row 0 and a_o
    dec_attend_post_kernel<<<dim3(B), 256, 0, stream>>>(
        hd0, E, post_W, post_b, attn, res, a_o, dec_i,
        /*s=*/0, /*attn_row=*/0, /*do_post=*/0, /*do_attn=*/1);

    for (int s = 0; s < LP; ++s) {
        const float* hin = (s & 1) ? hd1 : hd0;
        float*       hou = (s & 1) ? hd0 : hd1;
        dec_step_kernel<<<dim3(16, 16), 256, 0, stream>>>(
            Gd, dec_Wih, dec_Whh, dec_bhh, dec_i, a_o, hin, hou);
        dec_attend_post_kernel<<<dim3(B), 256, 0, stream>>>(
            hou, E, post_W, post_b, attn, res, a_o, dec_i,
            s, s + 1, 1, (s < LP - 1) ? 1 : 0);
    }
}

// Round 4
// 10543.589 us; speedup vs baseline: 1.3508x; 1.0637x over previous
//
#include <hip/hip_runtime.h>
#include <math.h>

#define B   256
#define LT  128
#define LP  64
#define DM  512
#define D3  1536
#define DPH 80
#define SCALE_F 0.044194173824159216f   // 1/sqrt(512)

__device__ __forceinline__ float dot4(float4 a, float4 b) {
    return a.x*b.x + a.y*b.y + a.z*b.z + a.w*b.w;
}
__device__ __forceinline__ float sigmoidf_(float x) {
    return 1.0f / (1.0f + expf(-x));
}

// ---------------------------------------------------------------------------
// Precompute G[r][n] = bias[n] + sum_j Emb[r][j] * W[n*wstride + woff + j]
// grid: (1536/256, R/4), block 256
// ---------------------------------------------------------------------------
__global__ __launch_bounds__(256) void precompG_kernel(
    const float* __restrict__ Emb, const float* __restrict__ W,
    const float* __restrict__ bias, float* __restrict__ G,
    int wstride, int woff)
{
    const int n  = blockIdx.x * 256 + threadIdx.x;
    const int r0 = blockIdx.y * 4;
    __shared__ float es[4][DM];
    for (int i = threadIdx.x; i < 4 * DM; i += 256)
        es[i >> 9][i & 511] = Emb[(r0 + (i >> 9)) * DM + (i & 511)];
    __syncthreads();
    float acc[4] = {0.f, 0.f, 0.f, 0.f};
    const float* wr = &W[(size_t)n * wstride + woff];
    for (int j = 0; j < DM; j += 4) {
        float4 w4 = *(const float4*)&wr[j];
        #pragma unroll
        for (int rr = 0; rr < 4; ++rr) {
            float4 e4 = *(const float4*)&es[rr][j];
            acc[rr] += dot4(e4, w4);
        }
    }
    float bv = bias[n];
    #pragma unroll
    for (int rr = 0; rr < 4; ++rr)
        G[(r0 + rr) * D3 + n] = acc[rr] + bv;
}

// ---------------------------------------------------------------------------
// Encoder GRU step, both directions (blockIdx.z), double-buffered LDS.
// Tiling: b-tile 16, j-tile 32 (x3 gates) -> grid (16,16,2) = 512 blocks
// (2 blocks/CU, 8 waves/CU for latency hiding). 1 barrier per k-iter.
// ---------------------------------------------------------------------------
__global__ __launch_bounds__(256) void enc_step_kernel(
    const float* __restrict__ Gf, const float* __restrict__ Gb,
    const float* __restrict__ Whh_f, const float* __restrict__ Whh_b,
    const float* __restrict__ bhh_f, const float* __restrict__ bhh_b,
    const int* __restrict__ text,
    const float* __restrict__ hF_in, float* __restrict__ hF_out,
    const float* __restrict__ hB_in, float* __restrict__ hB_out,
    float* __restrict__ E,
    int s)
{
    const int dir = blockIdx.z;
    const int t   = (dir == 0) ? s : (LT - 1 - s);
    const int yoff = (dir == 0) ? 0 : DM;
    const float* G   = (dir == 0) ? Gf    : Gb;
    const float* Whh = (dir == 0) ? Whh_f : Whh_b;
    const float* bhh = (dir == 0) ? bhh_f : bhh_b;
    const float* hin = (dir == 0) ? hF_in : hB_in;
    float* hout      = (dir == 0) ? hF_out : hB_out;

    __shared__ float As[2][16][36];
    __shared__ float Bs[2][96][36];

    const int tid = threadIdx.x;
    const int jj  = tid & 15;
    const int bb  = tid >> 4;          // 0..15
    const int jtile = blockIdx.x * 32;
    const int btile = blockIdx.y * 16;

    float acc[2][3];
    #pragma unroll
    for (int js = 0; js < 2; ++js)
        #pragma unroll
        for (int g = 0; g < 3; ++g) acc[js][g] = 0.f;

    const int lrow = tid >> 3;         // 0..31 (Bs); As uses tid<128 (0..15)
    const int lcol = (tid & 7) * 4;

    int wrow[3];
    #pragma unroll
    for (int rr = 0; rr < 3; ++rr) {
        int brow = lrow + rr * 32;
        wrow[rr] = (brow >> 5) * DM + jtile + (brow & 31);
    }

    // prefetch tile 0
    float4 rA = make_float4(0.f,0.f,0.f,0.f);
    if (tid < 128)
        rA = *(const float4*)&hin[(btile + lrow) * DM + lcol];
    float4 rB0 = *(const float4*)&Whh[(size_t)wrow[0] * DM + lcol];
    float4 rB1 = *(const float4*)&Whh[(size_t)wrow[1] * DM + lcol];
    float4 rB2 = *(const float4*)&Whh[(size_t)wrow[2] * DM + lcol];

    int buf = 0;
    for (int k = 0; k < 16; ++k) {
        if (tid < 128)
            *(float4*)&As[buf][lrow][lcol] = rA;
        *(float4*)&Bs[buf][lrow][lcol]      = rB0;
        *(float4*)&Bs[buf][lrow + 32][lcol] = rB1;
        *(float4*)&Bs[buf][lrow + 64][lcol] = rB2;
        __syncthreads();
        if (k < 15) {
            const int k0 = (k + 1) * 32;
            if (tid < 128)
                rA = *(const float4*)&hin[(btile + lrow) * DM + k0 + lcol];
            rB0 = *(const float4*)&Whh[(size_t)wrow[0] * DM + k0 + lcol];
            rB1 = *(const float4*)&Whh[(size_t)wrow[1] * DM + k0 + lcol];
            rB2 = *(const float4*)&Whh[(size_t)wrow[2] * DM + k0 + lcol];
        }
        #pragma unroll
        for (int c4 = 0; c4 < 8; ++c4) {
            float4 av = *(float4*)&As[buf][bb][c4 * 4];
            float4 bv[2][3];
            #pragma unroll
            for (int js = 0; js < 2; ++js)
                #pragma unroll
                for (int g = 0; g < 3; ++g)
                    bv[js][g] = *(float4*)&Bs[buf][g * 32 + jj + 16 * js][c4 * 4];
            #pragma unroll
            for (int js = 0; js < 2; ++js)
                #pragma unroll
                for (int g = 0; g < 3; ++g)
                    acc[js][g] += dot4(av, bv[js][g]);
        }
        buf ^= 1;
    }

    const int b = btile + bb;
    const int c = text[b * LT + t];
    #pragma unroll
    for (int js = 0; js < 2; ++js) {
        const int j = jtile + jj + 16 * js;
        float hr = acc[js][0] + bhh[j];
        float hz = acc[js][1] + bhh[DM + j];
        float hn = acc[js][2] + bhh[2 * DM + j];
        float r = sigmoidf_(G[c * D3 + j] + hr);
        float z = sigmoidf_(G[c * D3 + DM + j] + hz);
        float n = tanhf(G[c * D3 + 2 * DM + j] + r * hn);
        float hp = hin[b * DM + j];
        float hv = (1.f - z) * n + z * hp;
        hout[b * DM + j] = hv;
        E[(size_t)(b * LT + t) * 1024 + yoff + j] = hv;
    }
}

// ---------------------------------------------------------------------------
// Chunked k/v projection (rows [r0, r0+16384)), written to temp T then copied
// in-place over E by copy4_kernel. Tile 64x64(x2), kc=32. grid (8, 256)
// ---------------------------------------------------------------------------
__global__ __launch_bounds__(256) void kv_chunk_kernel(
    const float* __restrict__ E,
    const float* __restrict__ wk, const float* __restrict__ wv,
    const float* __restrict__ kb, const float* __restrict__ vb,
    float* __restrict__ T, int r0)
{
    __shared__ float As[64][36];
    __shared__ float Bk[64][36];
    __shared__ float Bv[64][36];
    const int tid = threadIdx.x;
    const int nn = tid & 15, bb = tid >> 4;
    const int ntile = blockIdx.x * 64;
    const int mtile = blockIdx.y * 64;

    float ak[4][4], av_[4][4];
    #pragma unroll
    for (int m = 0; m < 4; ++m)
        #pragma unroll
        for (int i = 0; i < 4; ++i) { ak[m][i] = 0.f; av_[m][i] = 0.f; }

    const int lrow = tid >> 3;
    const int lcol = (tid & 7) * 4;

    for (int k0 = 0; k0 < 1024; k0 += 32) {
        __syncthreads();
        *(float4*)&As[lrow][lcol] =
            *(const float4*)&E[(size_t)(r0 + mtile + lrow) * 1024 + k0 + lcol];
        *(float4*)&As[lrow + 32][lcol] =
            *(const float4*)&E[(size_t)(r0 + mtile + lrow + 32) * 1024 + k0 + lcol];
        *(float4*)&Bk[lrow][lcol] =
            *(const float4*)&wk[(ntile + lrow) * 1024 + k0 + lcol];
        *(float4*)&Bk[lrow + 32][lcol] =
            *(const float4*)&wk[(ntile + lrow + 32) * 1024 + k0 + lcol];
        *(float4*)&Bv[lrow][lcol] =
            *(const float4*)&wv[(ntile + lrow) * 1024 + k0 + lcol];
        *(float4*)&Bv[lrow + 32][lcol] =
            *(const float4*)&wv[(ntile + lrow + 32) * 1024 + k0 + lcol];
        __syncthreads();
        #pragma unroll
        for (int c4 = 0; c4 < 8; ++c4) {
            float4 a4[4], k4[4], v4[4];
            #pragma unroll
            for (int m = 0; m < 4; ++m) a4[m] = *(float4*)&As[bb + 16 * m][c4 * 4];
            #pragma unroll
            for (int i = 0; i < 4; ++i) {
                k4[i] = *(float4*)&Bk[nn + 16 * i][c4 * 4];
                v4[i] = *(float4*)&Bv[nn + 16 * i][c4 * 4];
            }
            #pragma unroll
            for (int m = 0; m < 4; ++m)
                #pragma unroll
                for (int i = 0; i < 4; ++i) {
                    ak[m][i]  += dot4(a4[m], k4[i]);
                    av_[m][i] += dot4(a4[m], v4[i]);
                }
        }
    }
    #pragma unroll
    for (int m = 0; m < 4; ++m) {
        const int lm = mtile + bb + 16 * m;
        #pragma unroll
        for (int i = 0; i < 4; ++i) {
            const int gn = ntile + nn + 16 * i;
            T[(size_t)lm * 1024 + gn]       = ak[m][i]  + kb[gn];
            T[(size_t)lm * 1024 + DM + gn]  = av_[m][i] + vb[gn];
        }
    }
}

// ---------------------------------------------------------------------------
// Grid-stride float4 copy (replaces hipMemcpyAsync D2D)
// ---------------------------------------------------------------------------
__global__ __launch_bounds__(256) void copy4_kernel(
    float4* __restrict__ dst, const float4* __restrict__ src, int n4)
{
    int i = blockIdx.x * 256 + threadIdx.x;
    const int stride = gridDim.x * 256;
    for (; i < n4; i += stride) dst[i] = src[i];
}

// ---------------------------------------------------------------------------
// h0 = tanh([hF|hB] @ hpost_W.T + hpost_b). One block per batch row.
// ---------------------------------------------------------------------------
__global__ __launch_bounds__(256) void hpost_kernel(
    const float* __restrict__ hF, const float* __restrict__ hB,
    const float* __restrict__ W, const float* __restrict__ bias,
    float* __restrict__ out)
{
    const int b = blockIdx.x;
    __shared__ float as_[1024];
    for (int i = threadIdx.x; i < DM; i += 256) {
        as_[i]      = hF[b * DM + i];
        as_[DM + i] = hB[b * DM + i];
    }
    __syncthreads();
    for (int n = threadIdx.x; n < DM; n += 256) {
        const float* wr = &W[n * 1024];
        float acc = 0.f;
        for (int j = 0; j < 1024; j += 4)
            acc += dot4(*(const float4*)&as_[j], *(const float4*)&wr[j]);
        out[b * DM + n] = tanhf(acc + bias[n]);
    }
}

// ---------------------------------------------------------------------------
// Decoder GRU step: b-tile 8, j-tile 32 -> grid (16,32) = 512 blocks
// (2 blocks/CU, 8 waves/CU), double-buffered LDS, 32-iter (phase,k0) loop.
// phase 0: A=a_o vs dec_Wih[:,512:]; phase 1: A=h vs dec_Whh.
// ---------------------------------------------------------------------------
__global__ __launch_bounds__(256) void dec_step_kernel(
    const float* __restrict__ Gd,
    const float* __restrict__ dec_Wih, const float* __restrict__ dec_Whh,
    const float* __restrict__ bhh,
    const int* __restrict__ dec_i,
    const float* __restrict__ a_o,
    const float* __restrict__ h_in, float* __restrict__ h_out)
{
    __shared__ float As[2][8][36];
    __shared__ float Bs[2][96][36];
    const int tid = threadIdx.x;
    const int jj = tid & 15;
    const int js = (tid >> 4) & 1;
    const int bb = tid >> 5;           // 0..7
    const int jtile = blockIdx.x * 32;
    const int btile = blockIdx.y * 8;

    float acc[4];   // 0:r 1:z 2:inn 3:hn
    #pragma unroll
    for (int g = 0; g < 4; ++g) acc[g] = 0.f;

    const int lrow = tid >> 3;          // 0..31 (Bs); As uses tid<64 (0..7)
    const int lcol = (tid & 7) * 4;

    int wrow[3];
    #pragma unroll
    for (int rr = 0; rr < 3; ++rr) {
        int brow = lrow + rr * 32;
        wrow[rr] = (brow >> 5) * DM + jtile + (brow & 31);
    }

    // prefetch kk=0 (phase 0)
    float4 rA = make_float4(0.f,0.f,0.f,0.f), rB0, rB1, rB2;
    if (tid < 64)
        rA = *(const float4*)&a_o[(btile + lrow) * DM + lcol];
    rB0 = *(const float4*)&dec_Wih[(size_t)wrow[0] * 1024 + DM + lcol];
    rB1 = *(const float4*)&dec_Wih[(size_t)wrow[1] * 1024 + DM + lcol];
    rB2 = *(const float4*)&dec_Wih[(size_t)wrow[2] * 1024 + DM + lcol];

    int buf = 0;
    for (int kk = 0; kk < 32; ++kk) {
        const int phase = kk >> 4;
        if (tid < 64)
            *(float4*)&As[buf][lrow][lcol] = rA;
        *(float4*)&Bs[buf][lrow][lcol]      = rB0;
        *(float4*)&Bs[buf][lrow + 32][lcol] = rB1;
        *(float4*)&Bs[buf][lrow + 64][lcol] = rB2;
        __syncthreads();
        if (kk < 31) {
            const int nk = kk + 1;
            const int np = nk >> 4;
            const int k0 = (nk & 15) * 32;
            if (tid < 64) {
                const float* Aptr = (np == 0) ? a_o : h_in;
                rA = *(const float4*)&Aptr[(btile + lrow) * DM + k0 + lcol];
            }
            if (np == 0) {
                rB0 = *(const float4*)&dec_Wih[(size_t)wrow[0] * 1024 + DM + k0 + lcol];
                rB1 = *(const float4*)&dec_Wih[(size_t)wrow[1] * 1024 + DM + k0 + lcol];
                rB2 = *(const float4*)&dec_Wih[(size_t)wrow[2] * 1024 + DM + k0 + lcol];
            } else {
                rB0 = *(const float4*)&dec_Whh[(size_t)wrow[0] * DM + k0 + lcol];
                rB1 = *(const float4*)&dec_Whh[(size_t)wrow[1] * DM + k0 + lcol];
                rB2 = *(const float4*)&dec_Whh[(size_t)wrow[2] * DM + k0 + lcol];
            }
        }
        #pragma unroll
        for (int c4 = 0; c4 < 8; ++c4) {
            float4 av = *(float4*)&As[buf][bb][c4 * 4];
            float4 bv[3];
            #pragma unroll
            for (int g = 0; g < 3; ++g)
                bv[g] = *(float4*)&Bs[buf][g * 32 + jj + 16 * js][c4 * 4];
            acc[0]         += dot4(av, bv[0]);
            acc[1]         += dot4(av, bv[1]);
            acc[2 + phase] += dot4(av, bv[2]);
        }
        buf ^= 1;
    }

    const int b = btile + bb;
    const int c = dec_i[b];
    const int j = jtile + jj + 16 * js;
    float r = sigmoidf_(Gd[c * D3 + j] + bhh[j] + acc[0]);
    float z = sigmoidf_(Gd[c * D3 + DM + j] + bhh[DM + j] + acc[1]);
    float n = tanhf(Gd[c * D3 + 2 * DM + j] + acc[2]
                    + r * (acc[3] + bhh[2 * DM + j]));
    float hp = h_in[b * DM + j];
    h_out[b * DM + j] = (1.f - z) * n + z * hp;
}

// ---------------------------------------------------------------------------
// Decoder tail: logits+argmax (do_post) and attention (do_attn).
// K row r at EKV[r*1024], V row at EKV[r*1024+512]. One block per batch row.
// QK: d-split across thread pairs; PV: l-split halves with LDS combine.
// ---------------------------------------------------------------------------
__global__ __launch_bounds__(256) void dec_attend_post_kernel(
    const float* __restrict__ q,
    const float* __restrict__ EKV,
    const float* __restrict__ post_W, const float* __restrict__ post_b,
    float* __restrict__ attn, float* __restrict__ res,
    float* __restrict__ a_o, int* __restrict__ dec_i,
    int s, int attn_row, int do_post, int do_attn)
{
    const int b = blockIdx.x;
    const int tid = threadIdx.x;
    __shared__ float qs[DM];
    __shared__ float part[256];
    __shared__ float sarr[LT];
    __shared__ float red[2];
    __shared__ float4 pvp[2][128];

    if (tid < 128)
        *(float4*)&qs[tid * 4] = *(const float4*)&q[b * DM + tid * 4];
    __syncthreads();

    if (do_post) {
        if (tid < DPH) {
            const float* wr = &post_W[tid * DM];
            float acc = 0.f;
            for (int d = 0; d < DM; d += 4)
                acc += dot4(*(const float4*)&qs[d], *(const float4*)&wr[d]);
            float lv = acc + post_b[tid];
            res[(b * LP + s) * DPH + tid] = lv;
            part[tid] = lv;
        }
        __syncthreads();
        if (tid == 0) {   // first-occurrence argmax, matching jnp.argmax
            float best = part[0]; int bi = 0;
            for (int p = 1; p < DPH; ++p) {
                float vv = part[p];
                if (vv > best) { best = vv; bi = p; }
            }
            dec_i[b] = bi;
        }
        __syncthreads();
    }

    if (do_attn) {
        // --- scores: 2 threads per K-row (d-halves) ---
        {
            const int r = tid & 127, half = tid >> 7;
            const float* kr = &EKV[(size_t)(b * LT + r) * 1024 + half * 256];
            const float* qh = &qs[half * 256];
            float p = 0.f;
            #pragma unroll
            for (int d = 0; d < 256; d += 4)
                p += dot4(*(const float4*)&qh[d], *(const float4*)&kr[d]);
            part[tid] = p;
        }
        __syncthreads();
        if (tid < LT) sarr[tid] = (part[tid] + part[tid + 128]) * SCALE_F;
        __syncthreads();
        if (tid < 64) {
            float m = fmaxf(sarr[tid], sarr[tid + 64]);
            #pragma unroll
            for (int off = 32; off > 0; off >>= 1)
                m = fmaxf(m, __shfl_xor(m, off));
            if (tid == 0) red[0] = m;
        }
        __syncthreads();
        const float smax = red[0];
        if (tid < LT) sarr[tid] = expf(sarr[tid] - smax);
        __syncthreads();
        if (tid < 64) {
            float ssum = sarr[tid] + sarr[tid + 64];
            #pragma unroll
            for (int off = 32; off > 0; off >>= 1)
                ssum += __shfl_xor(ssum, off);
            if (tid == 0) red[1] = ssum;
        }
        __syncthreads();
        const float inv = 1.0f / red[1];
        if (tid < LT) {
            float a = sarr[tid] * inv;
            sarr[tid] = a;
            attn[(size_t)(b * LP + attn_row) * LT + tid] = a;
        }
        __syncthreads();
        // --- o = a @ V: 2 threads per d-float4 (l-halves) ---
        {
            const int d4 = tid & 127, half = tid >> 7;
            const float* vb0 = &EKV[(size_t)b * LT * 1024 + DM];
            float4 acc = make_float4(0.f, 0.f, 0.f, 0.f);
            const int l0 = half * 64;
            #pragma unroll 8
            for (int l = l0; l < l0 + 64; ++l) {
                float a = sarr[l];
                float4 v4 = *(const float4*)&vb0[(size_t)l * 1024 + d4 * 4];
                acc.x += a * v4.x; acc.y += a * v4.y;
                acc.z += a * v4.z; acc.w += a * v4.w;
            }
            pvp[half][d4] = acc;
        }
        __syncthreads();
        if (tid < 128) {
            float4 p0 = pvp[0][tid], p1 = pvp[1][tid];
            float4 o = make_float4(p0.x + p1.x, p0.y + p1.y,
                                   p0.z + p1.z, p0.w + p1.w);
            *(float4*)&a_o[b * DM + tid * 4] = o;
        }
    }
}

// ---------------------------------------------------------------------------
extern "C" void kernel_launch(void* const* d_in, const int* in_sizes, int n_in,
                              void* d_out, int out_size, void* d_ws, size_t ws_size,
                              hipStream_t stream)
{
    const int*   text    = (const int*)d_in[0];
    const float* E_alpha = (const float*)d_in[2];
    const float* Wih_f   = (const float*)d_in[3];
    const float* Whh_f   = (const float*)d_in[4];
    const float* bih_f   = (const float*)d_in[5];
    const float* bhh_f   = (const float*)d_in[6];
    const float* Wih_b   = (const float*)d_in[7];
    const float* Whh_b   = (const float*)d_in[8];
    const float* bih_b   = (const float*)d_in[9];
    const float* bhh_b   = (const float*)d_in[10];
    const float* hpost_W = (const float*)d_in[11];
    const float* hpost_b = (const float*)d_in[12];
    const float* wk_W    = (const float*)d_in[13];
    const float* wk_b    = (const float*)d_in[14];
    const float* wv_W    = (const float*)d_in[15];
    const float* wv_b    = (const float*)d_in[16];
    const float* E_ph    = (const float*)d_in[17];
    const float* dec_Wih = (const float*)d_in[18];
    const float* dec_Whh = (const float*)d_in[19];
    const float* dec_bih = (const float*)d_in[20];
    const float* dec_bhh = (const float*)d_in[21];
    const float* post_W  = (const float*)d_in[22];
    const float* post_b  = (const float*)d_in[23];

    float* ws = (float*)d_ws;
    float* Gf  = ws;                 // 100*1536
    float* Gb  = Gf  + 153600;       // 100*1536
    float* Gd  = Gb  + 153600;       // 80*1536
    float* hF0 = Gd  + 122880;       // 256*512 x2 ping-pong
    float* hF1 = hF0 + 131072;
    float* hB0 = hF1 + 131072;
    float* hB1 = hB0 + 131072;
    float* hd0 = hB1 + 131072;       // decoder hidden ping-pong
    float* hd1 = hd0 + 131072;
    float* a_o = hd1 + 131072;       // 256*512
    int*   dec_i = (int*)(a_o + 131072);
    float* E   = a_o + 131072 + 512; // 32768*1024: ys, then in-place K|V
    float* T   = E + 33554432;       // 16384*1024 chunk temp (64 MB)
    // total ~197 MB of workspace

    hipMemsetAsync(hF0, 0, 131072 * sizeof(float), stream);
    hipMemsetAsync(hB0, 0, 131072 * sizeof(float), stream);
    hipMemsetAsync(dec_i, 0, B * sizeof(int), stream);

    // Fold input-side GRU GEMMs into per-token lookup tables
    precompG_kernel<<<dim3(6, 25), 256, 0, stream>>>(E_alpha, Wih_f, bih_f, Gf, DM, 0);
    precompG_kernel<<<dim3(6, 25), 256, 0, stream>>>(E_alpha, Wih_b, bih_b, Gb, DM, 0);
    precompG_kernel<<<dim3(6, 20), 256, 0, stream>>>(E_ph, dec_Wih, dec_bih, Gd, 1024, 0);

    // Bidirectional encoder: 128 steps, both directions per launch
    for (int s = 0; s < LT; ++s) {
        const float* fin = (s & 1) ? hF1 : hF0;
        float*       fou = (s & 1) ? hF0 : hF1;
        const float* bin = (s & 1) ? hB1 : hB0;
        float*       bou = (s & 1) ? hB0 : hB1;
        enc_step_kernel<<<dim3(16, 16, 2), 256, 0, stream>>>(
            Gf, Gb, Whh_f, Whh_b, bhh_f, bhh_b, text,
            fin, fou, bin, bou, E, s);
    }
    // s=127 wrote into hF0/hB0 -> finals live there

    // In-place ys -> [K|V]: 2 chunks of 16384 rows, copy via kernel
    for (int c = 0; c < 2; ++c) {
        const int r0 = c * 16384;
        kv_chunk_kernel<<<dim3(8, 256), 256, 0, stream>>>(
            E, wk_W, wv_W, wk_b, wv_b, T, r0);
        copy4_kernel<<<dim3(4096), 256, 0, stream>>>(
            (float4*)(E + (size_t)r0 * 1024), (const float4*)T,
            16384 * 1024 / 4);
    }

    hpost_kernel<<<dim3(B), 256, 0, stream>>>(hF0, hB0, hpost_W, hpost_b, hd0);

    float* attn = (float*)d_out;                  // (256,64,128)
    float* res  = attn + (size_t)B * LP * LT;     // (256,64,80)

    // a_sl0 = attend(h0): writes attn row 0 and a_o
    dec_attend_post_kernel<<<dim3(B), 256, 0, stream>>>(
        hd0, E, post_W, post_b, attn, res, a_o, dec_i,
        /*s=*/0, /*attn_row=*/0, /*do_post=*/0, /*do_attn=*/1);

    for (int s = 0; s < LP; ++s) {
        const float* hin = (s & 1) ? hd1 : hd0;
        float*       hou = (s & 1) ? hd0 : hd1;
        dec_step_kernel<<<dim3(16, 32), 256, 0, stream>>>(
            Gd, dec_Wih, dec_Whh, dec_bhh, dec_i, a_o, hin, hou);
        dec_attend_post_kernel<<<dim3(B), 256, 0, stream>>>(
            hou, E, post_W, post_b, attn, res, a_o, dec_i,
            s, s + 1, 1, (s < LP - 1) ? 1 : 0);
    }
}